// Round 10
// baseline (70.765 us; speedup 1.0000x reference)
//
#include <hip/hip_runtime.h>

// Problem: out[b,h,w,i,k] = inputs[b,h,w,i] * u[i,k],
//          u[i,k] = beta[i,k]^2 / sum_k beta[i,k]^2
// Shapes: inputs (4,256,256,32) f32, beta (32,8) f32, out (...,32,8) f32.
// Memory-bound: 256 MiB write + 33.5 MiB read.
//
// History: r6 x4+nt+hoist = 60.8us (best). r7 x32 = 69.7 (VGPR cliff).
// r8 x8 = 68.5. r9 LDS phase-separation = 68.1 — even a PURE write phase
// ran at ~4.3 TB/s while the harness fill kernel does 6.9 TB/s pure
// writes at 10% occupancy. Read interleave is NOT the limiter.
// Round-10: isolate the one untested variable vs the fill kernel — the
// nontemporal flag. Identical to r6 but with PLAIN stores (L2
// write-combining path, like fillBufferAligned). Single-variable A/B.

#define DIMD 32
#define DIMK 8

typedef float f32x4 __attribute__((ext_vector_type(4)));

__global__ __launch_bounds__(256) void mass_proto_kernel(
    const float* __restrict__ inputs,
    const float* __restrict__ beta,
    float* __restrict__ out,
    int n4)  // number of float4 output chunks = out_size/4
{
    __shared__ float bsq[DIMD * DIMK];
    __shared__ float u[DIMD * DIMK];

    // --- compute u (256 threads, one element each) ---
    const int t = threadIdx.x;              // 0..255
    float b = beta[t];
    bsq[t] = b * b;
    __syncthreads();
    const int row = t >> 3;                 // feature index i
    float s = 0.f;
#pragma unroll
    for (int j = 0; j < DIMK; ++j) s += bsq[row * DIMK + j];
    u[t] = bsq[t] / s;
    __syncthreads();

    const f32x4* __restrict__ u4 = reinterpret_cast<const f32x4*>(u);
    f32x4* __restrict__ out4 = reinterpret_cast<f32x4*>(out);

    // stride % 64 == 0 -> u4[(idx + j*stride)&63] is loop-invariant.
    const f32x4 uu = u4[t & 63];

    int idx = blockIdx.x * blockDim.x + threadIdx.x;
    const int stride = gridDim.x * blockDim.x;

    // --- main loop, x4 unrolled across the grid stride (same as r6) ---
    for (; idx + 3 * stride < n4; idx += 4 * stride) {
        const float x0 = inputs[(idx + 0 * stride) >> 1];
        const float x1 = inputs[(idx + 1 * stride) >> 1];
        const float x2 = inputs[(idx + 2 * stride) >> 1];
        const float x3 = inputs[(idx + 3 * stride) >> 1];

        out4[idx + 0 * stride] = x0 * uu;   // plain stores: L2 WC path,
        out4[idx + 1 * stride] = x1 * uu;   // same as fillBufferAligned
        out4[idx + 2 * stride] = x2 * uu;
        out4[idx + 3 * stride] = x3 * uu;
    }
    // tail (not taken for the bench shape: n4/stride == 32 exactly)
    for (; idx < n4; idx += stride)
        out4[idx] = inputs[idx >> 1] * uu;
}

extern "C" void kernel_launch(void* const* d_in, const int* in_sizes, int n_in,
                              void* d_out, int out_size, void* d_ws, size_t ws_size,
                              hipStream_t stream) {
    const float* inputs = (const float*)d_in[0];  // (4,256,256,32)
    const float* beta   = (const float*)d_in[1];  // (32,8)
    float* out = (float*)d_out;                   // (4,256,256,32,8)

    const int n4 = out_size / 4;                  // 16,777,216 float4s
    const int threads = 256;
    const int blocks = 2048;                      // 8 blocks/CU, 32 waves/CU

    mass_proto_kernel<<<blocks, threads, 0, stream>>>(inputs, beta, out, n4);
}

// Round 11
// 62.551 us; speedup vs baseline: 1.1313x; 1.1313x over previous
//
#include <hip/hip_runtime.h>

// Problem: out[b,h,w,i,k] = inputs[b,h,w,i] * u[i,k],
//          u[i,k] = beta[i,k]^2 / sum_k beta[i,k]^2
// Shapes: inputs (4,256,256,32) f32, beta (32,8) f32, out (...,32,8) f32.
// Memory-bound: 268 MB write + 33.5 MB read.
//
// Evidence table (effective write BW):
//   fill kernel   plain stores, no reads  : 6.9 TB/s
//   r6  (60.8us)  nt stores,  mixed reads : ~5.0
//   r10 (70.8us)  plain,      mixed reads : ~4.3  (L2 thrash vs read stream)
//   r9  (68.1us)  nt,         phase-sep   : ~4.3  (nt itself is the cap!)
// Conclusion: nt stores cap ~4.3-5 TB/s on gfx950; plain stores reach 6.9
// but only without a concurrent read stream. So: phase-separate (stage all
// input to LDS up front, one barrier) AND use plain stores. 18 KiB LDS ->
// 8 blocks/CU, full 32 waves/CU.

#define DIMD 32
#define DIMK 8
#define TRIPS 32   // chunks per thread = n4 / stride

typedef float f32x4 __attribute__((ext_vector_type(4)));

__global__ __launch_bounds__(256) void mass_proto_kernel(
    const float* __restrict__ inputs,
    const float* __restrict__ beta,
    float* __restrict__ out,
    int n4,       // total float4 output chunks = out_size/4
    int nelem4)   // total input float4s
{
    __shared__ __align__(16) float u[DIMD * DIMK];      // 1 KiB
    __shared__ float bsq[DIMD * DIMK];                  // 1 KiB
    __shared__ __align__(16) float xin[TRIPS * 128];    // 16 KiB staged input

    const int t = threadIdx.x;                   // 0..255
    const int stride   = gridDim.x * blockDim.x; // chunk stride per trip
    const int estride4 = stride >> 3;            // input float4s per trip

    // ---- issue ALL staging loads first (latency overlaps u-compute) ----
    const f32x4* __restrict__ in4 = reinterpret_cast<const f32x4*>(inputs);
    f32x4 v0, v1, v2, v3;
    {
        const int base = blockIdx.x * 32 + (t & 31);
        int g0 = base + ((t >> 5) + 0) * estride4 * 8 / 8;  // j = t>>5 + 8*r
        g0 = base + ((t >> 5) + 0 * 8) * estride4;
        const int g1 = base + ((t >> 5) + 1 * 8) * estride4;
        const int g2 = base + ((t >> 5) + 2 * 8) * estride4;
        const int g3 = base + ((t >> 5) + 3 * 8) * estride4;
        v0 = (g0 < nelem4) ? in4[g0] : (f32x4)0.f;
        v1 = (g1 < nelem4) ? in4[g1] : (f32x4)0.f;
        v2 = (g2 < nelem4) ? in4[g2] : (f32x4)0.f;
        v3 = (g3 < nelem4) ? in4[g3] : (f32x4)0.f;
    }

    // ---- compute u (256 threads, one element each) ----
    float b = beta[t];
    bsq[t] = b * b;
    __syncthreads();
    const int row = t >> 3;                      // feature index i
    float s = 0.f;
#pragma unroll
    for (int j = 0; j < DIMK; ++j) s += bsq[row * DIMK + j];
    u[t] = bsq[t] / s;

    // ---- park staged inputs in LDS ----
    f32x4* xin4 = reinterpret_cast<f32x4*>(xin);
    xin4[0 * 256 + t] = v0;
    xin4[1 * 256 + t] = v1;
    xin4[2 * 256 + t] = v2;
    xin4[3 * 256 + t] = v3;
    __syncthreads();                             // u and xin both ready

    // ---- pure write stream: operands from LDS, PLAIN stores ----
    const f32x4* __restrict__ u4 = reinterpret_cast<const f32x4*>(u);
    const f32x4 uu = u4[t & 63];                 // loop-invariant (stride%64==0)
    f32x4* __restrict__ out4 = reinterpret_cast<f32x4*>(out);

    const int idx = blockIdx.x * blockDim.x + t;
    const int th = t >> 1;                       // LDS slot (2-way broadcast, free)

    if (idx + (TRIPS - 1) * stride < n4) {
        // fast path — always taken for the bench shape (n4 == TRIPS*stride)
#pragma unroll 4
        for (int j = 0; j < TRIPS; ++j)
            out4[idx + j * stride] = xin[j * 128 + th] * uu;
    } else {
#pragma unroll 4
        for (int j = 0; j < TRIPS; ++j) {
            const int c = idx + j * stride;
            if (c < n4) out4[c] = xin[j * 128 + th] * uu;
        }
    }
}

extern "C" void kernel_launch(void* const* d_in, const int* in_sizes, int n_in,
                              void* d_out, int out_size, void* d_ws, size_t ws_size,
                              hipStream_t stream) {
    const float* inputs = (const float*)d_in[0];  // (4,256,256,32)
    const float* beta   = (const float*)d_in[1];  // (32,8)
    float* out = (float*)d_out;                   // (4,256,256,32,8)

    const int n4 = out_size / 4;                  // 16,777,216 float4 chunks
    const int threads = 256;
    const int blocks = (n4 + threads * TRIPS - 1) / (threads * TRIPS);  // 2048
    const int nelem4 = (out_size / DIMK) / 4;     // input float4 count

    mass_proto_kernel<<<blocks, threads, 0, stream>>>(inputs, beta, out, n4, nelem4);
}

// Round 12
// 55.287 us; speedup vs baseline: 1.2799x; 1.1314x over previous
//
#include <hip/hip_runtime.h>

// Problem: out[b,h,w,i,k] = inputs[b,h,w,i] * u[i,k],
//          u[i,k] = beta[i,k]^2 / sum_k beta[i,k]^2
// Shapes: inputs (4,256,256,32) f32, beta (32,8) f32, out (...,32,8) f32.
// Memory-bound: 268 MB write + 33.5 MB read.
//
// Evidence (effective write BW):
//   fill kernel  plain, no reads, 10% occupancy, dense front : 6.9 TB/s
//   r6  (60.8us) nt,    mixed,    100% occ, 8192 strided streams: ~5.0
//   r10 (70.8us) plain, mixed,    100% occ : ~4.3
//   r9  (68.1us) nt,    phase-sep,100% occ : ~4.3
//   r11 (62.6us) plain, phase-sep,100% occ : ~4.9
// All high-occupancy grid-stride variants cap ~5 TB/s; the fill kernel at
// 4 waves/CU hits 6.9. Theory: 8192 interleaved 1KiB write bursts with
// 8MiB hops destroy DRAM page locality. Round-12: 512 blocks (2/CU, 25%
// occupancy), each sweeping a CONTIGUOUS 512 KiB output region; input
// slice (64 KiB contiguous) staged to LDS first; plain stores.

#define DIMD 32
#define DIMK 8
#define CHUNKS_PER_BLOCK 32768   // f32x4 output chunks per block (512 KiB)
#define IN4_PER_BLOCK    4096    // f32x4 input per block (64 KiB)

typedef float f32x4 __attribute__((ext_vector_type(4)));

__global__ __launch_bounds__(256) void mass_proto_kernel(
    const float* __restrict__ inputs,
    const float* __restrict__ beta,
    float* __restrict__ out,
    int n4,       // total output f32x4 chunks
    int nelem4)   // total input f32x4s
{
    __shared__ __align__(16) float u[DIMD * DIMK];       // 1 KiB
    __shared__ __align__(16) float xf[IN4_PER_BLOCK * 4]; // 64 KiB staged input
    f32x4* xin4 = reinterpret_cast<f32x4*>(xf);

    const int t = threadIdx.x;                  // 0..255
    const int b = blockIdx.x;
    const int cbase = b * CHUNKS_PER_BLOCK;     // output chunk base
    const int ibase = b * IN4_PER_BLOCK;        // input f32x4 base

    // ---- phase 1: stage contiguous 64 KiB input slice into LDS ----
    const f32x4* __restrict__ in4 = reinterpret_cast<const f32x4*>(inputs);
    if (ibase + IN4_PER_BLOCK <= nelem4) {
#pragma unroll
        for (int j = 0; j < 16; ++j)            // 16 loads in flight, then park
            xin4[j * 256 + t] = in4[ibase + j * 256 + t];
    } else {
#pragma unroll
        for (int j = 0; j < 16; ++j) {
            const int g = ibase + j * 256 + t;
            xin4[j * 256 + t] = (g < nelem4) ? in4[g] : (f32x4)0.f;
        }
    }

    // ---- u[i,k] = beta^2 / rowsum(beta^2) via intra-wave shuffles ----
    // rows of 8 threads never cross a wave boundary -> no LDS, no barrier
    const float bv = beta[t];
    const float s2 = bv * bv;
    float sum = s2;
    sum += __shfl_xor(sum, 1);
    sum += __shfl_xor(sum, 2);
    sum += __shfl_xor(sum, 4);
    u[t] = s2 / sum;
    __syncthreads();                            // xin + u both ready

    // chunk index mod 64 == t mod 64 (CHUNKS_PER_BLOCK, 256 both %64==0)
    const f32x4 uu = reinterpret_cast<const f32x4*>(u)[t & 63];
    f32x4* __restrict__ out4 = reinterpret_cast<f32x4*>(out) + cbase;
    const int th = t >> 1;                      // LDS slot (2-way broadcast, free)

    // ---- phase 2: pure sequential write sweep over this block's 512 KiB ----
    if (cbase + CHUNKS_PER_BLOCK <= n4) {
#pragma unroll 8
        for (int j = 0; j < CHUNKS_PER_BLOCK / 256; ++j)
            out4[j * 256 + t] = xf[j * 128 + th] * uu;
    } else {
#pragma unroll 8
        for (int j = 0; j < CHUNKS_PER_BLOCK / 256; ++j) {
            const int c = j * 256 + t;
            if (cbase + c < n4) out4[c] = xf[j * 128 + th] * uu;
        }
    }
}

extern "C" void kernel_launch(void* const* d_in, const int* in_sizes, int n_in,
                              void* d_out, int out_size, void* d_ws, size_t ws_size,
                              hipStream_t stream) {
    const float* inputs = (const float*)d_in[0];  // (4,256,256,32)
    const float* beta   = (const float*)d_in[1];  // (32,8)
    float* out = (float*)d_out;                   // (4,256,256,32,8)

    const int n4 = out_size / 4;                  // 16,777,216 chunks
    const int nelem4 = in_sizes[0] / 4;           // 2,097,152 input f32x4
    const int blocks = (n4 + CHUNKS_PER_BLOCK - 1) / CHUNKS_PER_BLOCK;  // 512

    mass_proto_kernel<<<blocks, 256, 0, stream>>>(inputs, beta, out, n4, nelem4);
}